// Round 8
// baseline (99.782 us; speedup 1.0000x reference)
//
#include <hip/hip_runtime.h>
#include <math.h>

#define NT    8
#define NF    32
#define NPIX  2048
#define PXC   1024          // pixels per LDS chunk (2 chunks in rime)
#define NOUT  16384         // out elements when re-only (proven)
#define HHALF 1048576u
#define WS_META_BYTES 256   // d_ws[0..2]: sel,K0,K1; beams start at 256B

// ---- threefry2x32, 20 rounds (exact JAX/XLA) -- PROVEN, do not touch ----
__host__ __device__ inline unsigned rotl32(unsigned v, int r){ return (v<<r)|(v>>(32-r)); }
__host__ __device__ inline void tf2x32(unsigned k0, unsigned k1, unsigned c0, unsigned c1,
                                       unsigned* o0, unsigned* o1){
    const unsigned k2 = k0 ^ k1 ^ 0x1BD11BDAu;
    unsigned x0 = c0 + k0, x1 = c1 + k1;
#define G4(a,b,c,d) \
    x0+=x1; x1=rotl32(x1,a); x1^=x0; \
    x0+=x1; x1=rotl32(x1,b); x1^=x0; \
    x0+=x1; x1=rotl32(x1,c); x1^=x0; \
    x0+=x1; x1=rotl32(x1,d); x1^=x0;
    G4(13,15,26,6)  x0+=k1; x1+=k2+1u;
    G4(17,29,16,24) x0+=k2; x1+=k0+2u;
    G4(13,15,26,6)  x0+=k0; x1+=k1+3u;
    G4(17,29,16,24) x0+=k1; x1+=k2+4u;
    G4(13,15,26,6)  x0+=k2; x1+=k0+5u;
#undef G4
    *o0=x0; *o1=x1;
}

// R32: -log1p(-x^2) = -ln2 * log2(1 - x^2) via v_log_f32 (proven win)
__device__ inline float neglog1p_negsq(float x){
#if defined(__has_builtin)
#if __has_builtin(__builtin_amdgcn_logf)
    return -0.69314718055994531f * __builtin_amdgcn_logf(fmaf(-x, x, 1.0f));
#else
    return -0.69314718055994531f * log2f(fmaf(-x, x, 1.0f));
#endif
#else
    return -log1pf(-x*x);
#endif
}

__device__ inline float erfinv_f(float x){
    float w = neglog1p_negsq(x);
    float p;
    if (w < 5.0f){
        w -= 2.5f;
        p = 2.81022636e-08f;
        p = fmaf(p,w, 3.43273939e-07f);
        p = fmaf(p,w,-3.5233877e-06f);
        p = fmaf(p,w,-4.39150654e-06f);
        p = fmaf(p,w, 0.00021858087f);
        p = fmaf(p,w,-0.00125372503f);
        p = fmaf(p,w,-0.00417768164f);
        p = fmaf(p,w, 0.246640727f);
        p = fmaf(p,w, 1.50140941f);
    } else {
        w = sqrtf(w) - 3.0f;
        p = -0.000200214257f;
        p = fmaf(p,w, 0.000100950558f);
        p = fmaf(p,w, 0.00134934322f);
        p = fmaf(p,w,-0.00367342844f);
        p = fmaf(p,w, 0.00573950773f);
        p = fmaf(p,w,-0.0076224613f);
        p = fmaf(p,w, 0.00943887047f);
        p = fmaf(p,w, 1.00167406f);
        p = fmaf(p,w, 2.83297682f);
    }
    return p*x;
}

__device__ inline float bits_to_normal(unsigned bits){
    unsigned fb = (bits >> 9) | 0x3f800000u;
    float f = __uint_as_float(fb) - 1.0f;
    const float lo = -0.99999994f;
    float u = f * (1.0f - lo) + lo;
    return 1.41421356237f * erfinv_f(u);
}

//  0: legacy split-counter; 1: partitionable xor-fold; 2: lane0; 3: swapped xor
__device__ inline float normal_at(unsigned s0, unsigned s1, unsigned e, int sel){
    unsigned y0, y1, bits;
    if (sel == 0) {
        if (e < HHALF) { tf2x32(s0,s1, e,        e+HHALF, &y0,&y1); bits = y0; }
        else           { tf2x32(s0,s1, e-HHALF,  e,       &y0,&y1); bits = y1; }
    } else if (sel == 1) { tf2x32(s0,s1, 0u, e, &y0,&y1); bits = y0 ^ y1; }
    else if   (sel == 2) { tf2x32(s0,s1, 0u, e, &y0,&y1); bits = y0;      }
    else                 { tf2x32(s0,s1, e, 0u, &y0,&y1); bits = y0 ^ y1; }
    return bits_to_normal(bits);
}

__device__ inline void sincos_rev(float rev, float* s, float* c) {
#if defined(__has_builtin)
#if __has_builtin(__builtin_amdgcn_fractf)
    float q = __builtin_amdgcn_fractf(rev);      // v_fract_f32
#else
    float q = rev - floorf(rev);
#endif
#else
    float q = rev - floorf(rev);
#endif
#if defined(__has_builtin)
#if __has_builtin(__builtin_amdgcn_sinf) && __has_builtin(__builtin_amdgcn_cosf)
    *s = __builtin_amdgcn_sinf(q); *c = __builtin_amdgcn_cosf(q); return;
#endif
#endif
    __sincosf(6.28318530717958647692f * q, s, c);
}

// R33: 3-kernel split. History:
//   R28 (mono, 512thr): kernel 40.8us, VALUBusy 61%, Occ 20%, wall 99.6.
//   R30 (1024thr): 45.0us — TLP null #1.  R31 (2blk/CU): neutral — TLP null #2.
//   R32 (fast-log/fract/CSE/vec-stage): wall 90.6 — WIN; kernel ~32.6us.
//   Model (3 points): wall ~= 58us + total kernel time, ~1:1.
// Theory: staging (threefry+erfinv, ~14us) is occupancy-starved inside the
// barriered rime block (2 waves/SIMD). Move it to a dedicated kernel at
// 8 waves/SIMD (no LDS, no barriers) and let rime read pre-folded beams
// from d_ws (L2/LLC-resident). Ballot runs ONCE (sel_pick) not 256x.
// Predict: beam_gen ~5-7us, rime ~18-21us, sel ~2us, wall ~84-86us.
__global__ __launch_bounds__(64)
void sel_pick(const float* __restrict__ br,
              unsigned a0, unsigned a1, unsigned b0, unsigned b1,
              unsigned k3A0, unsigned k3A1, unsigned k3B0, unsigned k3B1,
              unsigned* __restrict__ meta)
{
    const int lane = threadIdx.x & 63;
    const float v = br[lane];
    unsigned u0a,u0b, uba,ubb, uca,ucb;
    tf2x32(a0,a1,(unsigned)lane,(unsigned)lane+HHALF,&u0a,&u0b); // sel0 (lane<HHALF)
    tf2x32(b0,b1,0u,(unsigned)lane,&uba,&ubb);                   // sel1 & sel2
    tf2x32(b0,b1,(unsigned)lane,0u,&uca,&ucb);                   // sel3
    unsigned long long q0 = __ballot(fabsf(bits_to_normal(u0a)    -v) < 1e-3f);
    unsigned long long q1 = __ballot(fabsf(bits_to_normal(uba^ubb)-v) < 1e-3f);
    unsigned long long q2 = __ballot(fabsf(bits_to_normal(uba)    -v) < 1e-3f);
    unsigned long long q3 = __ballot(fabsf(bits_to_normal(uca^ucb)-v) < 1e-3f);
    int c0=__popcll(q0), c1=__popcll(q1), c2=__popcll(q2), c3=__popcll(q3);
    int sel = 1, best = c1;
    if (c3 > best){ sel=3; best=c3; }
    if (c0 > best){ sel=0; best=c0; }
    if (c2 > best){ sel=2; best=c2; }
    if (lane == 0){
        meta[0] = (unsigned)sel;
        meta[1] = (sel==0)? k3A0 : k3B0;
        meta[2] = (sel==0)? k3A1 : k3B1;
    }
}

// 2048 blocks x 256 thr, 4 values/thread: all 4x256x2048 = 2,097,152
// sky-folded beam values. Each block covers one (m,tf) half-pixel-range:
// v = blk*1024 + i*256 + tid; m=v>>19, tf=(v>>11)&255, px=v&2047.
// No LDS, no barriers, low VGPR -> up to 8 waves/SIMD hides the serial
// threefry->erfinv chain. Writes beams[(tf*4+m)*2048+px] (coalesced).
__global__ __launch_bounds__(256)
void beam_gen(const float* __restrict__ br, const float* __restrict__ sky,
              const unsigned* __restrict__ meta, float2* __restrict__ beams)
{
    const int sel = (int)meta[0];
    const unsigned K0 = meta[1], K1 = meta[2];
    const unsigned base = (unsigned)blockIdx.x * 1024u;
    const unsigned m  = base >> 19;           // uniform within block
    const unsigned tf = (base >> 11) & 255u;  // uniform within block
    const unsigned f  = tf & 31u;
    const size_t   ob = ((size_t)tf*4u + m)*NPIX;
#pragma unroll
    for (int i = 0; i < 4; ++i) {
        const unsigned v  = base + (unsigned)i*256u + threadIdx.x;
        const unsigned px = v & 2047u;
        const float sqw = sqrtf(sky[f*NPIX + px]);
        const float n = normal_at(K0, K1, v, sel);
        beams[ob + px] = make_float2(br[v]*sqw, n*sqw);
    }
}

__global__ __launch_bounds__(512)
void rime_mono(const float2* __restrict__ beams,
               const float* __restrict__ blv,
               const float* __restrict__ stopo,
               const float* __restrict__ freqs,
               float* __restrict__ out, int out_size)
{
    __shared__ float2 s_cx[4][PXC];    // 32 KB: 4 models, sky-folded complex
    __shared__ float  s_st[3][PXC];    // 12 KB: s_topo x,y,z

    const int blk  = blockIdx.x;       // 256
    const int t    = blk >> 5;
    const int f    = blk & 31;
    const int wave = threadIdx.x >> 6;
    const int lane = threadIdx.x & 63;

    // wave -> 8 baselines, <=2 model pairs (derived from pairs[b]: b<=30 ->
    // (0,b+1); 31..60 -> (1,b-29); 61..63 -> (2,b-58); model = ant & 3)
    static const int BLS[8][8] = {
        { 0, 4, 8,12,16,20,24,28},   // pair (0,1)
        { 1, 5, 9,13,17,21,25,29},   // pair (0,2)
        { 2, 6,10,14,18,22,26,30},   // pair (0,3)
        { 3, 7,11,15,19,23,27,61},   // (0,0) x7 + (2,3)
        {31,35,39,43,47,51,55,59},   // pair (1,2)
        {32,36,40,44,48,52,56,60},   // pair (1,3)
        {33,37,41,45,49,53,57,62},   // (1,0) x7 + (2,0)
        {34,38,42,46,50,54,58,63}};  // (1,1) x7 + (2,1)
    static const int G1 [8] = {8,8,8,7,8,8,7,7};
    static const int P1A[8] = {0,0,0,0,1,1,1,1};
    static const int P1B[8] = {1,2,3,0,2,3,0,1};
    static const int P2A[8] = {0,0,0,2,1,1,2,2};
    static const int P2B[8] = {1,2,3,3,2,3,0,1};

    const int g1  = G1[wave];
    const int m1a = P1A[wave], m2a = P1B[wave];
    const int m1b = P2A[wave], m2b = P2B[wave];

    const float fscl = freqs[f] * (1.0f/299792458.0f);
    float bxf[8], byf[8], bzf[8];
    int   bidx[8];
#pragma unroll
    for (int j = 0; j < 8; ++j) {
        const int b = BLS[wave][j];
        bidx[j] = b;
        bxf[j] = blv[b*3+0] * fscl;    // fold freq/C into baseline vector
        byf[j] = blv[b*3+1] * fscl;
        bzf[j] = blv[b*3+2] * fscl;
    }

    float accR[8] = {0,0,0,0,0,0,0,0};
    float accI[8] = {0,0,0,0,0,0,0,0};

    const float2* __restrict__ bm = beams + (size_t)(t*NF + f)*4u*NPIX;

    for (int chunk = 0; chunk < 2; ++chunk) {
        const int p0 = chunk * PXC;
        // stage: pre-folded beams from d_ws (float4 = 2 px), stopo rows
        {
            const int pl = (int)threadIdx.x * 2;    // 0..1022, even
#pragma unroll
            for (int m = 0; m < 4; ++m) {
                *reinterpret_cast<float4*>(&s_cx[m][pl]) =
                    *reinterpret_cast<const float4*>(&bm[(size_t)m*NPIX + p0 + pl]);
            }
        }
        for (int i = threadIdx.x; i < 3*PXC; i += 512) {
            const int c  = i >> 10;
            const int pl = i & (PXC-1);
            s_st[c][pl] = stopo[(t*3 + c)*NPIX + p0 + pl];
        }
        __syncthreads();
        // compute: 16 pixel-iters per chunk; <=2 shared products per pixel
        for (int it = 0; it < PXC/64; ++it) {
            const int px = it*64 + lane;
            const float sx = s_st[0][px], sy = s_st[1][px], sz = s_st[2][px];
            const float2 u1 = s_cx[m1a][px], w1 = s_cx[m2a][px];
            const float2 u2 = s_cx[m1b][px], w2 = s_cx[m2b][px];
            const float pr1 = u1.x*w1.x + u1.y*w1.y;   // Re(c1*conj(c2))
            const float pi1 = u1.y*w1.x - u1.x*w1.y;   // Im
            const float pr2 = u2.x*w2.x + u2.y*w2.y;
            const float pi2 = u2.y*w2.x - u2.x*w2.y;
#pragma unroll
            for (int j = 0; j < 8; ++j) {
                const bool grp1 = (j < 7) || (g1 == 8);   // only j==7 runtime
                const float pr = grp1 ? pr1 : pr2;
                const float pi = grp1 ? pi1 : pi2;
                float rev = bxf[j]*sx;
                rev = fmaf(byf[j], sy, rev);
                rev = fmaf(bzf[j], sz, rev);              // = freq*tau (revolutions)
                float sn, cs;
                sincos_rev(rev, &sn, &cs);
                accR[j] = fmaf(pr, cs, fmaf(-pi, sn, accR[j]));
                accI[j] = fmaf(pr, sn, fmaf( pi, cs, accI[j]));
            }
        }
        __syncthreads();   // protect LDS before next chunk's staging
    }

    // wave-level butterfly reduction; lane 0 writes
#pragma unroll
    for (int j = 0; j < 8; ++j) {
        float r = accR[j], i = accI[j];
#pragma unroll
        for (int off = 32; off > 0; off >>= 1) {
            r += __shfl_xor(r, off, 64);
            i += __shfl_xor(i, off, 64);
        }
        if (lane == 0) {
            const int idx = (bidx[j]*NT + t)*NF + f;
            if (out_size == NOUT) out[idx] = r;                 // re-only (proven)
            else ((float2*)out)[idx] = make_float2(r, i);       // hedge
        }
    }
}

extern "C" void kernel_launch(void* const* d_in, const int* in_sizes, int n_in,
                              void* d_out, int out_size, void* d_ws, size_t ws_size,
                              hipStream_t stream)
{
    const float* br    = (const float*)d_in[0];
    const float* sky   = (const float*)d_in[1];
    const float* blv   = (const float*)d_in[2];
    const float* stopo = (const float*)d_in[3];
    const float* freqs = (const float*)d_in[4];
    float*       out   = (float*)      d_out;

    unsigned* meta  = (unsigned*)d_ws;
    float2*   beams = (float2*)((char*)d_ws + WS_META_BYTES);  // 16 MB

    // Subkey candidates for key(0)=(0,0), split(key,6) -- verbatim (proven):
    unsigned x0,x1,y0,y1;
    tf2x32(0u,0u, 4u,10u, &x0,&x1); const unsigned ck2A0 = x0;
    tf2x32(0u,0u, 5u,11u, &y0,&y1); const unsigned ck2A1 = y0;
    tf2x32(0u,0u, 0u, 6u, &x0,&x1); const unsigned k3A0  = x1;
    tf2x32(0u,0u, 1u, 7u, &y0,&y1); const unsigned k3A1  = y1;
    unsigned ck2B0, ck2B1; tf2x32(0u,0u, 0u,2u, &ck2B0,&ck2B1);
    unsigned k3B0,  k3B1;  tf2x32(0u,0u, 0u,3u, &k3B0, &k3B1);

    sel_pick<<<dim3(1), dim3(64), 0, stream>>>(
        br, ck2A0,ck2A1, ck2B0,ck2B1, k3A0,k3A1, k3B0,k3B1, meta);

    beam_gen<<<dim3(2048), dim3(256), 0, stream>>>(br, sky, meta, beams);

    rime_mono<<<dim3(NT*NF), dim3(512), 0, stream>>>(
        beams, blv, stopo, freqs, out, out_size);
}

// Round 9
// 87.986 us; speedup vs baseline: 1.1341x; 1.1341x over previous
//
#include <hip/hip_runtime.h>
#include <math.h>

#define NT    8
#define NF    32
#define NPIX  2048
#define PXC   1024          // pixels per LDS chunk (2 chunks)
#define NOUT  16384         // out elements when re-only (proven)
#define HHALF 1048576u

// ---- threefry2x32, 20 rounds (exact JAX/XLA) -- PROVEN, do not touch ----
__host__ __device__ inline unsigned rotl32(unsigned v, int r){ return (v<<r)|(v>>(32-r)); }
__host__ __device__ inline void tf2x32(unsigned k0, unsigned k1, unsigned c0, unsigned c1,
                                       unsigned* o0, unsigned* o1){
    const unsigned k2 = k0 ^ k1 ^ 0x1BD11BDAu;
    unsigned x0 = c0 + k0, x1 = c1 + k1;
#define G4(a,b,c,d) \
    x0+=x1; x1=rotl32(x1,a); x1^=x0; \
    x0+=x1; x1=rotl32(x1,b); x1^=x0; \
    x0+=x1; x1=rotl32(x1,c); x1^=x0; \
    x0+=x1; x1=rotl32(x1,d); x1^=x0;
    G4(13,15,26,6)  x0+=k1; x1+=k2+1u;
    G4(17,29,16,24) x0+=k2; x1+=k0+2u;
    G4(13,15,26,6)  x0+=k0; x1+=k1+3u;
    G4(17,29,16,24) x0+=k1; x1+=k2+4u;
    G4(13,15,26,6)  x0+=k2; x1+=k0+5u;
#undef G4
    *o0=x0; *o1=x1;
}

// R32: -log1p(-x^2) = -ln2 * log2(1 - x^2) via v_log_f32 (proven win)
__device__ inline float neglog1p_negsq(float x){
#if defined(__has_builtin)
#if __has_builtin(__builtin_amdgcn_logf)
    return -0.69314718055994531f * __builtin_amdgcn_logf(fmaf(-x, x, 1.0f));
#else
    return -0.69314718055994531f * log2f(fmaf(-x, x, 1.0f));
#endif
#else
    return -log1pf(-x*x);
#endif
}

__device__ inline float erfinv_f(float x){
    float w = neglog1p_negsq(x);
    float p;
    if (w < 5.0f){
        w -= 2.5f;
        p = 2.81022636e-08f;
        p = fmaf(p,w, 3.43273939e-07f);
        p = fmaf(p,w,-3.5233877e-06f);
        p = fmaf(p,w,-4.39150654e-06f);
        p = fmaf(p,w, 0.00021858087f);
        p = fmaf(p,w,-0.00125372503f);
        p = fmaf(p,w,-0.00417768164f);
        p = fmaf(p,w, 0.246640727f);
        p = fmaf(p,w, 1.50140941f);
    } else {
        w = sqrtf(w) - 3.0f;
        p = -0.000200214257f;
        p = fmaf(p,w, 0.000100950558f);
        p = fmaf(p,w, 0.00134934322f);
        p = fmaf(p,w,-0.00367342844f);
        p = fmaf(p,w, 0.00573950773f);
        p = fmaf(p,w,-0.0076224613f);
        p = fmaf(p,w, 0.00943887047f);
        p = fmaf(p,w, 1.00167406f);
        p = fmaf(p,w, 2.83297682f);
    }
    return p*x;
}

__device__ inline float bits_to_normal(unsigned bits){
    unsigned fb = (bits >> 9) | 0x3f800000u;
    float f = __uint_as_float(fb) - 1.0f;
    const float lo = -0.99999994f;
    float u = f * (1.0f - lo) + lo;
    return 1.41421356237f * erfinv_f(u);
}

//  0: legacy split-counter; 1: partitionable xor-fold; 2: lane0; 3: swapped xor
__device__ inline float normal_at(unsigned s0, unsigned s1, unsigned e, int sel){
    unsigned y0, y1, bits;
    if (sel == 0) {
        if (e < HHALF) { tf2x32(s0,s1, e,        e+HHALF, &y0,&y1); bits = y0; }
        else           { tf2x32(s0,s1, e-HHALF,  e,       &y0,&y1); bits = y1; }
    } else if (sel == 1) { tf2x32(s0,s1, 0u, e, &y0,&y1); bits = y0 ^ y1; }
    else if   (sel == 2) { tf2x32(s0,s1, 0u, e, &y0,&y1); bits = y0;      }
    else                 { tf2x32(s0,s1, e, 0u, &y0,&y1); bits = y0 ^ y1; }
    return bits_to_normal(bits);
}

__device__ inline void sincos_rev(float rev, float* s, float* c) {
#if defined(__has_builtin)
#if __has_builtin(__builtin_amdgcn_fractf)
    float q = __builtin_amdgcn_fractf(rev);      // v_fract_f32
#else
    float q = rev - floorf(rev);
#endif
#else
    float q = rev - floorf(rev);
#endif
#if defined(__has_builtin)
#if __has_builtin(__builtin_amdgcn_sinf) && __has_builtin(__builtin_amdgcn_cosf)
    *s = __builtin_amdgcn_sinf(q); *c = __builtin_amdgcn_cosf(q); return;
#endif
#endif
    __sincosf(6.28318530717958647692f * q, s, c);
}

// R34: R32 single-kernel + RE_ONLY template specialization.
// History: R28 mono: 40.8us kernel, wall 99.6. R30 (1024thr): TLP null #1.
//   R31 (2blk/CU): TLP null #2. R32 (fast-log/fract/CSE/vec): wall 90.6 WIN,
//   kernel ~32.6us. R33 (3-kernel split): wall 99.8 REGRESSION — each extra
//   dependent dispatch costs ~3-5us (launch gaps + 16MB ws round-trip);
//   FUSION WINS on this harness, do not split.
// Model (4 pts): wall ~= 58us + total kernel time, ~1:1.
// Change vs R32: out_size==NOUT every clean run -> accI (2 FMA x 256/thread)
// and the I-half of the butterfly are dead work in the re-only case.
// template<bool REO>, both instantiations kept, host picks (hedge intact).
// Also hoisted m-invariant sky sqrt out of the staging m-loop explicitly.
// Predict: kernel ~29.5-31us, wall ~87-89, VALUBusy ~flat, VGPR ~44.
template<bool REO>
__global__ __launch_bounds__(512)
void rime_mono(const float* __restrict__ br,
               const float* __restrict__ sky,
               const float* __restrict__ blv,
               const float* __restrict__ stopo,
               const float* __restrict__ freqs,
               unsigned a0, unsigned a1, unsigned b0, unsigned b1,
               unsigned k3A0, unsigned k3A1, unsigned k3B0, unsigned k3B1,
               float* __restrict__ out, int out_size)
{
    __shared__ float2 s_cx[4][PXC];    // 32 KB: 4 models, sky-folded complex
    __shared__ float  s_st[3][PXC];    // 12 KB: s_topo x,y,z

    const int blk  = blockIdx.x;       // 256
    const int t    = blk >> 5;
    const int f    = blk & 31;
    const int wave = threadIdx.x >> 6;
    const int lane = threadIdx.x & 63;

    // RNG scheme select via per-wave ballot over br[0..63] (proven logic,
    // R32 CSE form: sel1/sel2 share one tf2x32)
    int sel;
    {
        const float v = br[lane];
        unsigned u0a,u0b, uba,ubb, uca,ucb;
        tf2x32(a0,a1,(unsigned)lane,(unsigned)lane+HHALF,&u0a,&u0b); // sel0 (lane<HHALF)
        tf2x32(b0,b1,0u,(unsigned)lane,&uba,&ubb);                   // sel1 & sel2
        tf2x32(b0,b1,(unsigned)lane,0u,&uca,&ucb);                   // sel3
        unsigned long long q0 = __ballot(fabsf(bits_to_normal(u0a)    -v) < 1e-3f);
        unsigned long long q1 = __ballot(fabsf(bits_to_normal(uba^ubb)-v) < 1e-3f);
        unsigned long long q2 = __ballot(fabsf(bits_to_normal(uba)    -v) < 1e-3f);
        unsigned long long q3 = __ballot(fabsf(bits_to_normal(uca^ucb)-v) < 1e-3f);
        int c0=__popcll(q0), c1=__popcll(q1), c2=__popcll(q2), c3=__popcll(q3);
        sel = 1; int best = c1;
        if (c3 > best){ sel=3; best=c3; }
        if (c0 > best){ sel=0; best=c0; }
        if (c2 > best){ sel=2; best=c2; }
    }
    const unsigned K0 = (sel==0)? k3A0 : k3B0;
    const unsigned K1 = (sel==0)? k3A1 : k3B1;

    // wave -> 8 baselines, <=2 model pairs (derived from pairs[b]: b<=30 ->
    // (0,b+1); 31..60 -> (1,b-29); 61..63 -> (2,b-58); model = ant & 3)
    static const int BLS[8][8] = {
        { 0, 4, 8,12,16,20,24,28},   // pair (0,1)
        { 1, 5, 9,13,17,21,25,29},   // pair (0,2)
        { 2, 6,10,14,18,22,26,30},   // pair (0,3)
        { 3, 7,11,15,19,23,27,61},   // (0,0) x7 + (2,3)
        {31,35,39,43,47,51,55,59},   // pair (1,2)
        {32,36,40,44,48,52,56,60},   // pair (1,3)
        {33,37,41,45,49,53,57,62},   // (1,0) x7 + (2,0)
        {34,38,42,46,50,54,58,63}};  // (1,1) x7 + (2,1)
    static const int G1 [8] = {8,8,8,7,8,8,7,7};
    static const int P1A[8] = {0,0,0,0,1,1,1,1};
    static const int P1B[8] = {1,2,3,0,2,3,0,1};
    static const int P2A[8] = {0,0,0,2,1,1,2,2};
    static const int P2B[8] = {1,2,3,3,2,3,0,1};

    const int g1  = G1[wave];
    const int m1a = P1A[wave], m2a = P1B[wave];
    const int m1b = P2A[wave], m2b = P2B[wave];

    const float fscl = freqs[f] * (1.0f/299792458.0f);
    float bxf[8], byf[8], bzf[8];
    int   bidx[8];
#pragma unroll
    for (int j = 0; j < 8; ++j) {
        const int b = BLS[wave][j];
        bidx[j] = b;
        bxf[j] = blv[b*3+0] * fscl;    // fold freq/C into baseline vector
        byf[j] = blv[b*3+1] * fscl;
        bzf[j] = blv[b*3+2] * fscl;
    }

    float accR[8] = {0,0,0,0,0,0,0,0};
    float accI[8] = {0,0,0,0,0,0,0,0};

    const unsigned ebase_tf = (unsigned)(t*NF + f) * NPIX;

    for (int chunk = 0; chunk < 2; ++chunk) {
        const int p0 = chunk * PXC;
        // stage: cx[m][pl] = (br, bi)*sqrt(sky); bi generated via threefry.
        // float2 global loads, float4 LDS write; sky sqrt hoisted (m-invariant);
        // 8 independent threefry chains -> ILP.
        {
            const int pl = (int)threadIdx.x * 2;    // 0..1022, even
            const float2 k2 = *reinterpret_cast<const float2*>(&sky[f*NPIX + p0 + pl]);
            const float sq0 = sqrtf(k2.x), sq1 = sqrtf(k2.y);
#pragma unroll
            for (int m = 0; m < 4; ++m) {
                const unsigned e = (unsigned)m*524288u + ebase_tf + (unsigned)(p0 + pl);
                const float2 b2 = *reinterpret_cast<const float2*>(&br[e]);
                const float n0 = normal_at(K0,K1,e,   sel);
                const float n1 = normal_at(K0,K1,e+1u,sel);
                float4 w4;
                w4.x = b2.x*sq0; w4.y = n0*sq0;
                w4.z = b2.y*sq1; w4.w = n1*sq1;
                *reinterpret_cast<float4*>(&s_cx[m][pl]) = w4;
            }
        }
        for (int i = threadIdx.x; i < 3*PXC; i += 512) {
            const int c  = i >> 10;
            const int pl = i & (PXC-1);
            s_st[c][pl] = stopo[(t*3 + c)*NPIX + p0 + pl];
        }
        __syncthreads();
        // compute: 16 pixel-iters per chunk; <=2 shared products per pixel
        for (int it = 0; it < PXC/64; ++it) {
            const int px = it*64 + lane;
            const float sx = s_st[0][px], sy = s_st[1][px], sz = s_st[2][px];
            const float2 u1 = s_cx[m1a][px], w1 = s_cx[m2a][px];
            const float2 u2 = s_cx[m1b][px], w2 = s_cx[m2b][px];
            const float pr1 = u1.x*w1.x + u1.y*w1.y;   // Re(c1*conj(c2))
            const float pi1 = u1.y*w1.x - u1.x*w1.y;   // Im
            const float pr2 = u2.x*w2.x + u2.y*w2.y;
            const float pi2 = u2.y*w2.x - u2.x*w2.y;
#pragma unroll
            for (int j = 0; j < 8; ++j) {
                const bool grp1 = (j < 7) || (g1 == 8);   // only j==7 runtime
                const float pr = grp1 ? pr1 : pr2;
                const float pi = grp1 ? pi1 : pi2;
                float rev = bxf[j]*sx;
                rev = fmaf(byf[j], sy, rev);
                rev = fmaf(bzf[j], sz, rev);              // = freq*tau (revolutions)
                float sn, cs;
                sincos_rev(rev, &sn, &cs);
                accR[j] = fmaf(pr, cs, fmaf(-pi, sn, accR[j]));
                if (!REO)
                    accI[j] = fmaf(pr, sn, fmaf( pi, cs, accI[j]));
            }
        }
        __syncthreads();   // protect LDS before next chunk's staging
    }

    // wave-level butterfly reduction; lane 0 writes
#pragma unroll
    for (int j = 0; j < 8; ++j) {
        float r = accR[j];
#pragma unroll
        for (int off = 32; off > 0; off >>= 1)
            r += __shfl_xor(r, off, 64);
        if (REO) {
            if (lane == 0) out[(bidx[j]*NT + t)*NF + f] = r;    // re-only (proven)
        } else {
            float i = accI[j];
#pragma unroll
            for (int off = 32; off > 0; off >>= 1)
                i += __shfl_xor(i, off, 64);
            if (lane == 0)
                ((float2*)out)[(bidx[j]*NT + t)*NF + f] = make_float2(r, i); // hedge
        }
    }
}

extern "C" void kernel_launch(void* const* d_in, const int* in_sizes, int n_in,
                              void* d_out, int out_size, void* d_ws, size_t ws_size,
                              hipStream_t stream)
{
    const float* br    = (const float*)d_in[0];
    const float* sky   = (const float*)d_in[1];
    const float* blv   = (const float*)d_in[2];
    const float* stopo = (const float*)d_in[3];
    const float* freqs = (const float*)d_in[4];
    float*       out   = (float*)      d_out;

    // Subkey candidates for key(0)=(0,0), split(key,6) -- verbatim (proven):
    unsigned x0,x1,y0,y1;
    tf2x32(0u,0u, 4u,10u, &x0,&x1); const unsigned ck2A0 = x0;
    tf2x32(0u,0u, 5u,11u, &y0,&y1); const unsigned ck2A1 = y0;
    tf2x32(0u,0u, 0u, 6u, &x0,&x1); const unsigned k3A0  = x1;
    tf2x32(0u,0u, 1u, 7u, &y0,&y1); const unsigned k3A1  = y1;
    unsigned ck2B0, ck2B1; tf2x32(0u,0u, 0u,2u, &ck2B0,&ck2B1);
    unsigned k3B0,  k3B1;  tf2x32(0u,0u, 0u,3u, &k3B0, &k3B1);

    if (out_size == NOUT)
        rime_mono<true><<<dim3(NT*NF), dim3(512), 0, stream>>>(
            br, sky, blv, stopo, freqs,
            ck2A0,ck2A1, ck2B0,ck2B1, k3A0,k3A1, k3B0,k3B1,
            out, out_size);
    else
        rime_mono<false><<<dim3(NT*NF), dim3(512), 0, stream>>>(
            br, sky, blv, stopo, freqs,
            ck2A0,ck2A1, ck2B0,ck2B1, k3A0,k3A1, k3B0,k3B1,
            out, out_size);
}

// Round 10
// 87.495 us; speedup vs baseline: 1.1404x; 1.0056x over previous
//
#include <hip/hip_runtime.h>
#include <math.h>

#define NT    8
#define NF    32
#define NPIX  2048
#define PXC   1024          // pixels per LDS chunk (2 chunks)
#define NOUT  16384         // out elements when re-only (proven)
#define HHALF 1048576u

// ---- threefry2x32, 20 rounds (exact JAX/XLA) -- PROVEN, do not touch ----
__host__ __device__ inline unsigned rotl32(unsigned v, int r){ return (v<<r)|(v>>(32-r)); }
__host__ __device__ inline void tf2x32(unsigned k0, unsigned k1, unsigned c0, unsigned c1,
                                       unsigned* o0, unsigned* o1){
    const unsigned k2 = k0 ^ k1 ^ 0x1BD11BDAu;
    unsigned x0 = c0 + k0, x1 = c1 + k1;
#define G4(a,b,c,d) \
    x0+=x1; x1=rotl32(x1,a); x1^=x0; \
    x0+=x1; x1=rotl32(x1,b); x1^=x0; \
    x0+=x1; x1=rotl32(x1,c); x1^=x0; \
    x0+=x1; x1=rotl32(x1,d); x1^=x0;
    G4(13,15,26,6)  x0+=k1; x1+=k2+1u;
    G4(17,29,16,24) x0+=k2; x1+=k0+2u;
    G4(13,15,26,6)  x0+=k0; x1+=k1+3u;
    G4(17,29,16,24) x0+=k1; x1+=k2+4u;
    G4(13,15,26,6)  x0+=k2; x1+=k0+5u;
#undef G4
    *o0=x0; *o1=x1;
}

// R32: -log1p(-x^2) = -ln2 * log2(1 - x^2) via v_log_f32 (proven win)
__device__ inline float neglog1p_negsq(float x){
#if defined(__has_builtin)
#if __has_builtin(__builtin_amdgcn_logf)
    return -0.69314718055994531f * __builtin_amdgcn_logf(fmaf(-x, x, 1.0f));
#else
    return -0.69314718055994531f * log2f(fmaf(-x, x, 1.0f));
#endif
#else
    return -log1pf(-x*x);
#endif
}

__device__ inline float erfinv_f(float x){
    float w = neglog1p_negsq(x);
    float p;
    if (w < 5.0f){
        w -= 2.5f;
        p = 2.81022636e-08f;
        p = fmaf(p,w, 3.43273939e-07f);
        p = fmaf(p,w,-3.5233877e-06f);
        p = fmaf(p,w,-4.39150654e-06f);
        p = fmaf(p,w, 0.00021858087f);
        p = fmaf(p,w,-0.00125372503f);
        p = fmaf(p,w,-0.00417768164f);
        p = fmaf(p,w, 0.246640727f);
        p = fmaf(p,w, 1.50140941f);
    } else {
        w = sqrtf(w) - 3.0f;
        p = -0.000200214257f;
        p = fmaf(p,w, 0.000100950558f);
        p = fmaf(p,w, 0.00134934322f);
        p = fmaf(p,w,-0.00367342844f);
        p = fmaf(p,w, 0.00573950773f);
        p = fmaf(p,w,-0.0076224613f);
        p = fmaf(p,w, 0.00943887047f);
        p = fmaf(p,w, 1.00167406f);
        p = fmaf(p,w, 2.83297682f);
    }
    return p*x;
}

__device__ inline float bits_to_normal(unsigned bits){
    unsigned fb = (bits >> 9) | 0x3f800000u;
    float f = __uint_as_float(fb) - 1.0f;
    const float lo = -0.99999994f;
    float u = f * (1.0f - lo) + lo;
    return 1.41421356237f * erfinv_f(u);
}

//  0: legacy split-counter; 1: partitionable xor-fold; 2: lane0; 3: swapped xor
__device__ inline float normal_at(unsigned s0, unsigned s1, unsigned e, int sel){
    unsigned y0, y1, bits;
    if (sel == 0) {
        if (e < HHALF) { tf2x32(s0,s1, e,        e+HHALF, &y0,&y1); bits = y0; }
        else           { tf2x32(s0,s1, e-HHALF,  e,       &y0,&y1); bits = y1; }
    } else if (sel == 1) { tf2x32(s0,s1, 0u, e, &y0,&y1); bits = y0 ^ y1; }
    else if   (sel == 2) { tf2x32(s0,s1, 0u, e, &y0,&y1); bits = y0;      }
    else                 { tf2x32(s0,s1, e, 0u, &y0,&y1); bits = y0 ^ y1; }
    return bits_to_normal(bits);
}

__device__ inline void sincos_rev(float rev, float* s, float* c) {
#if defined(__has_builtin)
#if __has_builtin(__builtin_amdgcn_fractf)
    float q = __builtin_amdgcn_fractf(rev);      // v_fract_f32
#else
    float q = rev - floorf(rev);
#endif
#else
    float q = rev - floorf(rev);
#endif
#if defined(__has_builtin)
#if __has_builtin(__builtin_amdgcn_sinf) && __has_builtin(__builtin_amdgcn_cosf)
    *s = __builtin_amdgcn_sinf(q); *c = __builtin_amdgcn_cosf(q); return;
#endif
#endif
    __sincosf(6.28318530717958647692f * q, s, c);
}

// R35: three zero-risk issue cuts on the R34 structure.
// History: R28 mono 40.8us/wall 99.6. R30/R31: TLP null x2. R32 (fast-log
//   /fract/CSE/vec): wall 90.6 WIN. R33 (3-kernel split): 99.8 REGRESSION
//   (launch gaps ~3-5us each; fusion wins). R34 (REO dead-accI): wall 88.0
//   WIN, kernel ~30us. Model: wall ~= 58us + kernel (5 pts). Cuts pay
//   AMPLIFIED (~6x raw issue count: each op also carries stall exposure).
// Changes: (1) scalar-branch skip of pair2 (readfirstlane; 5/8 waves drop
//   2 LDS b64 + 8 VALU per px); (2) s_topo packed float4 -> 1 ds_read_b128
//   (was 3 b32); (3) 2 px/lane/iter (8 iters x 128 px): 2x indep chains
//   per j, half loop overhead. Numerics identical (sum order permutes only).
// Predict: kernel ~26.5-28us, wall ~84.5-86.5, VALUBusy flat+, VGPR +8.
template<bool REO>
__global__ __launch_bounds__(512)
void rime_mono(const float* __restrict__ br,
               const float* __restrict__ sky,
               const float* __restrict__ blv,
               const float* __restrict__ stopo,
               const float* __restrict__ freqs,
               unsigned a0, unsigned a1, unsigned b0, unsigned b1,
               unsigned k3A0, unsigned k3A1, unsigned k3B0, unsigned k3B1,
               float* __restrict__ out, int out_size)
{
    __shared__ float2 s_cx[4][PXC];    // 32 KB: 4 models, sky-folded complex
    __shared__ float4 s_st4[PXC];      // 16 KB: s_topo packed (x,y,z,0)

    const int blk  = blockIdx.x;       // 256
    const int t    = blk >> 5;
    const int f    = blk & 31;
    const int wave = threadIdx.x >> 6;
    const int lane = threadIdx.x & 63;

    // RNG scheme select via per-wave ballot over br[0..63] (proven logic,
    // R32 CSE form: sel1/sel2 share one tf2x32)
    int sel;
    {
        const float v = br[lane];
        unsigned u0a,u0b, uba,ubb, uca,ucb;
        tf2x32(a0,a1,(unsigned)lane,(unsigned)lane+HHALF,&u0a,&u0b); // sel0 (lane<HHALF)
        tf2x32(b0,b1,0u,(unsigned)lane,&uba,&ubb);                   // sel1 & sel2
        tf2x32(b0,b1,(unsigned)lane,0u,&uca,&ucb);                   // sel3
        unsigned long long q0 = __ballot(fabsf(bits_to_normal(u0a)    -v) < 1e-3f);
        unsigned long long q1 = __ballot(fabsf(bits_to_normal(uba^ubb)-v) < 1e-3f);
        unsigned long long q2 = __ballot(fabsf(bits_to_normal(uba)    -v) < 1e-3f);
        unsigned long long q3 = __ballot(fabsf(bits_to_normal(uca^ucb)-v) < 1e-3f);
        int c0=__popcll(q0), c1=__popcll(q1), c2=__popcll(q2), c3=__popcll(q3);
        sel = 1; int best = c1;
        if (c3 > best){ sel=3; best=c3; }
        if (c0 > best){ sel=0; best=c0; }
        if (c2 > best){ sel=2; best=c2; }
    }
    const unsigned K0 = (sel==0)? k3A0 : k3B0;
    const unsigned K1 = (sel==0)? k3A1 : k3B1;

    // wave -> 8 baselines, <=2 model pairs (derived from pairs[b]: b<=30 ->
    // (0,b+1); 31..60 -> (1,b-29); 61..63 -> (2,b-58); model = ant & 3)
    static const int BLS[8][8] = {
        { 0, 4, 8,12,16,20,24,28},   // pair (0,1)
        { 1, 5, 9,13,17,21,25,29},   // pair (0,2)
        { 2, 6,10,14,18,22,26,30},   // pair (0,3)
        { 3, 7,11,15,19,23,27,61},   // (0,0) x7 + (2,3)
        {31,35,39,43,47,51,55,59},   // pair (1,2)
        {32,36,40,44,48,52,56,60},   // pair (1,3)
        {33,37,41,45,49,53,57,62},   // (1,0) x7 + (2,0)
        {34,38,42,46,50,54,58,63}};  // (1,1) x7 + (2,1)
    static const int G1 [8] = {8,8,8,7,8,8,7,7};
    static const int P1A[8] = {0,0,0,0,1,1,1,1};
    static const int P1B[8] = {1,2,3,0,2,3,0,1};
    static const int P2A[8] = {0,0,0,2,1,1,2,2};
    static const int P2B[8] = {1,2,3,3,2,3,0,1};

    const int g1  = G1[wave];
    const int m1a = P1A[wave], m2a = P1B[wave];
    const int m1b = P2A[wave], m2b = P2B[wave];
    // scalar (readfirstlane) wave-uniform flags -> s_cbranch, no divergence
    const bool twop = (__builtin_amdgcn_readfirstlane(g1) == 7);  // wave needs pair2

    const float fscl = freqs[f] * (1.0f/299792458.0f);
    float bxf[8], byf[8], bzf[8];
    int   bidx[8];
#pragma unroll
    for (int j = 0; j < 8; ++j) {
        const int b = BLS[wave][j];
        bidx[j] = b;
        bxf[j] = blv[b*3+0] * fscl;    // fold freq/C into baseline vector
        byf[j] = blv[b*3+1] * fscl;
        bzf[j] = blv[b*3+2] * fscl;
    }

    float accR[8] = {0,0,0,0,0,0,0,0};
    float accI[8] = {0,0,0,0,0,0,0,0};

    const unsigned ebase_tf = (unsigned)(t*NF + f) * NPIX;

    for (int chunk = 0; chunk < 2; ++chunk) {
        const int p0 = chunk * PXC;
        // stage: cx[m][pl] = (br, bi)*sqrt(sky); bi generated via threefry.
        // float2 global loads, float4 LDS write; sky sqrt hoisted (m-invariant);
        // 8 independent threefry chains -> ILP.
        {
            const int pl = (int)threadIdx.x * 2;    // 0..1022, even
            const float2 k2 = *reinterpret_cast<const float2*>(&sky[f*NPIX + p0 + pl]);
            const float sq0 = sqrtf(k2.x), sq1 = sqrtf(k2.y);
#pragma unroll
            for (int m = 0; m < 4; ++m) {
                const unsigned e = (unsigned)m*524288u + ebase_tf + (unsigned)(p0 + pl);
                const float2 b2 = *reinterpret_cast<const float2*>(&br[e]);
                const float n0 = normal_at(K0,K1,e,   sel);
                const float n1 = normal_at(K0,K1,e+1u,sel);
                float4 w4;
                w4.x = b2.x*sq0; w4.y = n0*sq0;
                w4.z = b2.y*sq1; w4.w = n1*sq1;
                *reinterpret_cast<float4*>(&s_cx[m][pl]) = w4;
            }
            // s_topo packed: (x,y,z,0) per pixel, 2 px/thread
            const float2 sx2 = *reinterpret_cast<const float2*>(&stopo[(t*3+0)*NPIX + p0 + pl]);
            const float2 sy2 = *reinterpret_cast<const float2*>(&stopo[(t*3+1)*NPIX + p0 + pl]);
            const float2 sz2 = *reinterpret_cast<const float2*>(&stopo[(t*3+2)*NPIX + p0 + pl]);
            s_st4[pl]   = make_float4(sx2.x, sy2.x, sz2.x, 0.0f);
            s_st4[pl+1] = make_float4(sx2.y, sy2.y, sz2.y, 0.0f);
        }
        __syncthreads();
        // compute: 8 iters x 128 px (2 px per lane) per chunk
        for (int it = 0; it < PXC/128; ++it) {
            const int pxA = it*128 + lane;
            const int pxB = pxA + 64;
            const float4 stA = s_st4[pxA];
            const float4 stB = s_st4[pxB];
            const float2 u1A = s_cx[m1a][pxA], w1A = s_cx[m2a][pxA];
            const float2 u1B = s_cx[m1a][pxB], w1B = s_cx[m2a][pxB];
            const float pr1A = u1A.x*w1A.x + u1A.y*w1A.y;  // Re(c1*conj(c2))
            const float pi1A = u1A.y*w1A.x - u1A.x*w1A.y;  // Im
            const float pr1B = u1B.x*w1B.x + u1B.y*w1B.y;
            const float pi1B = u1B.y*w1B.x - u1B.x*w1B.y;
            float pr2A = 0.f, pi2A = 0.f, pr2B = 0.f, pi2B = 0.f;
            if (twop) {                          // scalar branch: 3/8 waves
                const float2 u2A = s_cx[m1b][pxA], w2A = s_cx[m2b][pxA];
                const float2 u2B = s_cx[m1b][pxB], w2B = s_cx[m2b][pxB];
                pr2A = u2A.x*w2A.x + u2A.y*w2A.y;
                pi2A = u2A.y*w2A.x - u2A.x*w2A.y;
                pr2B = u2B.x*w2B.x + u2B.y*w2B.y;
                pi2B = u2B.y*w2B.x - u2B.x*w2B.y;
            }
#pragma unroll
            for (int j = 0; j < 8; ++j) {
                const bool grp1 = (j < 7) || !twop;        // scalar select
                const float prA = grp1 ? pr1A : pr2A;
                const float piA = grp1 ? pi1A : pi2A;
                const float prB = grp1 ? pr1B : pr2B;
                const float piB = grp1 ? pi1B : pi2B;
                float revA = bxf[j]*stA.x;
                revA = fmaf(byf[j], stA.y, revA);
                revA = fmaf(bzf[j], stA.z, revA);          // freq*tau (rev)
                float revB = bxf[j]*stB.x;
                revB = fmaf(byf[j], stB.y, revB);
                revB = fmaf(bzf[j], stB.z, revB);
                float snA, csA, snB, csB;
                sincos_rev(revA, &snA, &csA);
                sincos_rev(revB, &snB, &csB);
                accR[j] = fmaf(prA, csA, fmaf(-piA, snA, accR[j]));
                accR[j] = fmaf(prB, csB, fmaf(-piB, snB, accR[j]));
                if (!REO) {
                    accI[j] = fmaf(prA, snA, fmaf( piA, csA, accI[j]));
                    accI[j] = fmaf(prB, snB, fmaf( piB, csB, accI[j]));
                }
            }
        }
        __syncthreads();   // protect LDS before next chunk's staging
    }

    // wave-level butterfly reduction; lane 0 writes
#pragma unroll
    for (int j = 0; j < 8; ++j) {
        float r = accR[j];
#pragma unroll
        for (int off = 32; off > 0; off >>= 1)
            r += __shfl_xor(r, off, 64);
        if (REO) {
            if (lane == 0) out[(bidx[j]*NT + t)*NF + f] = r;    // re-only (proven)
        } else {
            float i = accI[j];
#pragma unroll
            for (int off = 32; off > 0; off >>= 1)
                i += __shfl_xor(i, off, 64);
            if (lane == 0)
                ((float2*)out)[(bidx[j]*NT + t)*NF + f] = make_float2(r, i); // hedge
        }
    }
}

extern "C" void kernel_launch(void* const* d_in, const int* in_sizes, int n_in,
                              void* d_out, int out_size, void* d_ws, size_t ws_size,
                              hipStream_t stream)
{
    const float* br    = (const float*)d_in[0];
    const float* sky   = (const float*)d_in[1];
    const float* blv   = (const float*)d_in[2];
    const float* stopo = (const float*)d_in[3];
    const float* freqs = (const float*)d_in[4];
    float*       out   = (float*)      d_out;

    // Subkey candidates for key(0)=(0,0), split(key,6) -- verbatim (proven):
    unsigned x0,x1,y0,y1;
    tf2x32(0u,0u, 4u,10u, &x0,&x1); const unsigned ck2A0 = x0;
    tf2x32(0u,0u, 5u,11u, &y0,&y1); const unsigned ck2A1 = y0;
    tf2x32(0u,0u, 0u, 6u, &x0,&x1); const unsigned k3A0  = x1;
    tf2x32(0u,0u, 1u, 7u, &y0,&y1); const unsigned k3A1  = y1;
    unsigned ck2B0, ck2B1; tf2x32(0u,0u, 0u,2u, &ck2B0,&ck2B1);
    unsigned k3B0,  k3B1;  tf2x32(0u,0u, 0u,3u, &k3B0, &k3B1);

    if (out_size == NOUT)
        rime_mono<true><<<dim3(NT*NF), dim3(512), 0, stream>>>(
            br, sky, blv, stopo, freqs,
            ck2A0,ck2A1, ck2B0,ck2B1, k3A0,k3A1, k3B0,k3B1,
            out, out_size);
    else
        rime_mono<false><<<dim3(NT*NF), dim3(512), 0, stream>>>(
            br, sky, blv, stopo, freqs,
            ck2A0,ck2A1, ck2B0,ck2B1, k3A0,k3A1, k3B0,k3B1,
            out, out_size);
}